// Round 1
// baseline (1096.478 us; speedup 1.0000x reference)
//
#include <hip/hip_runtime.h>

// mean_i (1 - output[i, targets[i]])  over N=8192 rows, C=32000 cols, fp32.
// Pure gather + reduce: only 8192 scattered floats are needed from the 1GB
// matrix. One block, 1024 threads, 8 rows/thread, shuffle+LDS reduction,
// thread 0 writes the scalar. No atomics -> no d_out init needed (d_out is
// fully overwritten every launch; re-poison safe).

#define N_ROWS      8192
#define NUM_CLASSES 32000
#define BLOCK       1024
#define ROWS_PER_T  (N_ROWS / BLOCK)   // 8

__global__ __launch_bounds__(BLOCK)
void CosineLoss_90374701842716_kernel(const float* __restrict__ out_mat,
                                      const int*   __restrict__ targets,
                                      float*       __restrict__ result) {
    const int tid = threadIdx.x;

    // Gather: 8 independent loads per thread (good MLP on one CU).
    float s = 0.0f;
    #pragma unroll
    for (int k = 0; k < ROWS_PER_T; ++k) {
        const int row = tid + k * BLOCK;
        const int t   = targets[row];
        s += out_mat[(size_t)row * NUM_CLASSES + (size_t)t];
    }

    // Wave-64 shuffle reduction.
    #pragma unroll
    for (int off = 32; off > 0; off >>= 1)
        s += __shfl_down(s, off, 64);

    __shared__ float wave_sums[BLOCK / 64];   // 16 waves
    const int wave = tid >> 6;
    const int lane = tid & 63;
    if (lane == 0) wave_sums[wave] = s;
    __syncthreads();

    if (wave == 0) {
        float v = (lane < (BLOCK / 64)) ? wave_sums[lane] : 0.0f;
        #pragma unroll
        for (int off = 8; off > 0; off >>= 1)
            v += __shfl_down(v, off, 64);
        if (lane == 0)
            *result = 1.0f - v * (1.0f / (float)N_ROWS);
    }
}

extern "C" void kernel_launch(void* const* d_in, const int* in_sizes, int n_in,
                              void* d_out, int out_size, void* d_ws, size_t ws_size,
                              hipStream_t stream) {
    const float* out_mat = (const float*)d_in[0];
    const int*   targets = (const int*)d_in[1];
    float*       result  = (float*)d_out;

    CosineLoss_90374701842716_kernel<<<1, BLOCK, 0, stream>>>(out_mat, targets, result);
}